// Round 4
// baseline (321.627 us; speedup 1.0000x reference)
//
#include <hip/hip_runtime.h>

typedef float f4 __attribute__((ext_vector_type(4)));

#define L_SEQ 2048
#define D4    16             // 64/4 floats per row as float4
#define NC4   512            // float4 chunks per output row
#define RAD   128
#define ROWS  32             // rows per block
#define NBH   48
#define NTIL  64             // L_SEQ/ROWS
#define NBLK  (NBH * NTIL)   // 3072
#define WIN   68             // fixed per-row band window, chunks (band span <= 66)
#define ZN    (NC4 - WIN)    // 444 zero chunks per row

// Barrier-free streaming kernel. Block = one (b,h) x 32-row slab, 256 threads.
// 1) every thread streams ~55 nontemporal zero stores (no input needed -> the
//    HBM write stream starts at cycle 0 and never gates on compute), then
// 2) every thread computes one 4-row x 8-col register tile of the band,
//    reading K/Q straight from L1/L2 (no LDS, no __syncthreads anywhere).
// Window/zero split is disjoint and exact: row's window [wlo, wlo+68) is
// written by compute items (with per-element masking), the other 444 chunks
// by the zero pass.
__global__ __launch_bounds__(256, 4)
void band_scores(const float* __restrict__ Qg, const float* __restrict__ Kg,
                 float* __restrict__ outg)
{
    const int t  = threadIdx.x;
    const int id = blockIdx.x;
    // bijective XCD swizzle (NBLK % 8 == 0): same-bh blocks share an XCD's L2
    const int swz = (id & 7) * (NBLK / 8) + (id >> 3);
    const int bh  = swz >> 6;
    const int i0  = (swz & (NTIL - 1)) * ROWS;

    const f4* __restrict__ K4 = reinterpret_cast<const f4*>(Kg) + (size_t)bh * L_SEQ * D4;
    const f4* __restrict__ Q4 = reinterpret_cast<const f4*>(Qg) + (size_t)bh * L_SEQ * D4;
    f4* __restrict__ O4       = reinterpret_cast<f4*>(outg)     + (size_t)bh * L_SEQ * NC4;

    const f4 zero = (f4)0.f;

    // ---- phase A: zero stores, fully streaming, 2 per row per thread
#pragma unroll
    for (int r = 0; r < ROWS; ++r) {
        int s   = i0 + (r & ~3) - RAD;            // rowgroup window base
        int wlo = s < 0 ? 0 : (s >> 2);
        wlo = wlo > ZN ? ZN : wlo;
        f4* rowp = O4 + (size_t)(i0 + r) * NC4;
        const int j4 = t < wlo ? t : t + WIN;     // t in [0,444) always
        __builtin_nontemporal_store(zero, rowp + j4);
        const int k2 = t + 256;
        if (k2 < ZN) {
            const int j4b = k2 < wlo ? k2 : k2 + WIN;
            __builtin_nontemporal_store(zero, rowp + j4b);
        }
    }

    // ---- phase B: band tiles. 272 items = 8 rowgroups x 34; item m covers
    // rows [i0+4rg, +4) x chunks {wlo+c, wlo+34+c} (unit-stride lane stores).
    auto item = [&](int m) {
        const int rg = m / 34;
        const int c  = m - rg * 34;
        int s   = i0 + rg * 4 - RAD;
        int wlo = s < 0 ? 0 : (s >> 2);
        wlo = wlo > ZN ? ZN : wlo;
        const int cA = wlo + c;                   // chunk A index
        const int jA = cA << 2;                   // K row base, chunk A
        const int jB = (cA + 34) << 2;            // K row base, chunk B
        const int r0 = i0 + rg * 4;

        float acc[4][8];
#pragma unroll
        for (int r = 0; r < 4; ++r)
#pragma unroll
            for (int cc = 0; cc < 8; ++cc) acc[r][cc] = 0.f;

#pragma unroll 2
        for (int d4 = 0; d4 < D4; ++d4) {
            f4 ka[4], kb[4], qv[4];
#pragma unroll
            for (int cc = 0; cc < 4; ++cc) ka[cc] = K4[(size_t)(jA + cc) * D4 + d4];
#pragma unroll
            for (int cc = 0; cc < 4; ++cc) kb[cc] = K4[(size_t)(jB + cc) * D4 + d4];
#pragma unroll
            for (int r = 0; r < 4; ++r)  qv[r] = Q4[(size_t)(r0 + r) * D4 + d4];
#pragma unroll
            for (int r = 0; r < 4; ++r) {
                const float qx = qv[r].x, qy = qv[r].y, qz = qv[r].z, qw = qv[r].w;
#pragma unroll
                for (int cc = 0; cc < 4; ++cc) {
                    acc[r][cc]     += qx * ka[cc].x + qy * ka[cc].y
                                    + qz * ka[cc].z + qw * ka[cc].w;
                    acc[r][4 + cc] += qx * kb[cc].x + qy * kb[cc].y
                                    + qz * kb[cc].z + qw * kb[cc].w;
                }
            }
        }

#pragma unroll
        for (int r = 0; r < 4; ++r) {
            const int i = r0 + r;
            f4 vA, vB;
            vA.x = ((unsigned)(i - (jA + 0) + RAD) <= 2u * RAD) ? acc[r][0] : 0.f;
            vA.y = ((unsigned)(i - (jA + 1) + RAD) <= 2u * RAD) ? acc[r][1] : 0.f;
            vA.z = ((unsigned)(i - (jA + 2) + RAD) <= 2u * RAD) ? acc[r][2] : 0.f;
            vA.w = ((unsigned)(i - (jA + 3) + RAD) <= 2u * RAD) ? acc[r][3] : 0.f;
            vB.x = ((unsigned)(i - (jB + 0) + RAD) <= 2u * RAD) ? acc[r][4] : 0.f;
            vB.y = ((unsigned)(i - (jB + 1) + RAD) <= 2u * RAD) ? acc[r][5] : 0.f;
            vB.z = ((unsigned)(i - (jB + 2) + RAD) <= 2u * RAD) ? acc[r][6] : 0.f;
            vB.w = ((unsigned)(i - (jB + 3) + RAD) <= 2u * RAD) ? acc[r][7] : 0.f;
            __builtin_nontemporal_store(vA, O4 + (size_t)i * NC4 + cA);
            __builtin_nontemporal_store(vB, O4 + (size_t)i * NC4 + cA + 34);
        }
    };

    item(t);
    if (t < 16) item(256 + t);   // extras: rg 7, c = 18..33
}

extern "C" void kernel_launch(void* const* d_in, const int* in_sizes, int n_in,
                              void* d_out, int out_size, void* d_ws, size_t ws_size,
                              hipStream_t stream) {
    const float* Q = (const float*)d_in[0];
    const float* K = (const float*)d_in[1];
    float* out = (float*)d_out;
    band_scores<<<NBLK, 256, 0, stream>>>(Q, K, out);
}

// Round 5
// 240.096 us; speedup vs baseline: 1.3396x; 1.3396x over previous
//
#include <hip/hip_runtime.h>

typedef float f4 __attribute__((ext_vector_type(4)));

#define L_SEQ 2048
#define D4    16             // 64 floats = 16 float4 per row
#define NC4   512            // float4 chunks per output row
#define RAD   128
#define WIN   68             // per-row band window width in chunks (band span <= 66)
#define ZN    (NC4 - WIN)    // 444 zero chunks per row
#define NBH   48

// Window contract shared by both kernels: row i's window is
// [w(i), w(i)+68) with w(i) = clamp((i-128)>>2, 0, 444); w is constant
// across each 4-aligned rowgroup. Kernel Z writes everything outside the
// window; kernel B writes everything inside it (band-masked). Disjoint+exact.

// ---------------- Kernel Z: streaming zero-fill of out-of-band ----------------
#define ZROWS 16
#define ZBLK  (NBH * (L_SEQ / ZROWS))   // 6144

__global__ __launch_bounds__(256)
void zero_oob(float* __restrict__ outg)
{
    const int t  = threadIdx.x;
    const int id = blockIdx.x;
    const int bh = id >> 7;                 // / 128 row-slabs
    const int r0 = (id & 127) * ZROWS;
    f4* __restrict__ O4 = reinterpret_cast<f4*>(outg) + (size_t)bh * L_SEQ * NC4;
    const f4 zero = (f4)0.f;
#pragma unroll
    for (int r = 0; r < ZROWS; ++r) {
        const int i = r0 + r;
        int w = (i - RAD) >> 2; w = w < 0 ? 0 : (w > ZN ? ZN : w);
        f4* rowp = O4 + (size_t)i * NC4;
        const int jA = t < w ? t : t + WIN;          // t in [0,444) always
        __builtin_nontemporal_store(zero, rowp + jA);
        const int z2 = t + 256;
        if (z2 < ZN) {
            const int jB = z2 < w ? z2 : z2 + WIN;
            __builtin_nontemporal_store(zero, rowp + jB);
        }
    }
}

// ---------------- Kernel B: band compute, window-only stores ----------------
#define TI    32
#define NTIL  (L_SEQ / TI)              // 64
#define BBLK  (NBH * NTIL)              // 3072
#define KROWS (TI + 2 * RAD)            // 288 staged K rows

__global__ __launch_bounds__(256, 2)
void band_compute(const float* __restrict__ Qg, const float* __restrict__ Kg,
                  float* __restrict__ outg)
{
    __shared__ f4 sK[KROWS * D4];   // 73728 B -> 2 blocks/CU; slot = si*16 + (d4 ^ ((si>>3)&7))

    const int t  = threadIdx.x;
    const int id = blockIdx.x;
    // bijective XCD swizzle (BBLK % 8 == 0): same-bh blocks share an XCD's L2
    const int swz = (id & 7) * (BBLK / 8) + (id >> 3);
    const int bh  = swz >> 6;
    const int i0  = (swz & (NTIL - 1)) * TI;
    const int i04 = i0 >> 2;

    const f4* __restrict__ K4 = reinterpret_cast<const f4*>(Kg) + (size_t)bh * L_SEQ * D4;
    const f4* __restrict__ Q4 = reinterpret_cast<const f4*>(Qg) + (size_t)bh * L_SEQ * D4;
    f4* __restrict__ O4       = reinterpret_cast<f4*>(outg)     + (size_t)bh * L_SEQ * NC4;

    // ---- stage K band rows [i0-128, i0+160) (clamped; clamped slots only feed
    // masked outputs), swizzled so item reads (si stride 4/lane) are <=2-way.
    const int kbase = i0 - RAD;
#pragma unroll
    for (int itr = 0; itr < (KROWS * D4) / 256; ++itr) {
        const int s  = itr * 256 + t;
        const int si = s >> 4, d4 = s & 15;
        int row = kbase + si;
        row = row < 0 ? 0 : (row > L_SEQ - 1 ? L_SEQ - 1 : row);
        sK[(si << 4) + (d4 ^ ((si >> 3) & 7))] = K4[(size_t)row * D4 + d4];
    }
    __syncthreads();

    // ---- 272 items = 8 rowgroups x 34; item (rg,m) = 4 rows x chunks {w+m, w+34+m}.
    // Q comes straight from global: per load instr a wave touches ~2 distinct
    // 16B lines (34 threads share a rowgroup) -> L1 broadcast, cheap.
    auto run_item = [&](int rg, int m) {
        int wb = i04 + rg - 32;
        int w  = wb < 0 ? 0 : (wb > ZN ? ZN : wb);
        const int cA = w + m;
        const int cB = cA + 34;
        const int r0 = i0 + (rg << 2);

        int sA[4], xA[4], sB[4], xB[4];
#pragma unroll
        for (int c = 0; c < 4; ++c) {
            int a = (cA << 2) + c - kbase;
            a = a < 0 ? 0 : (a > KROWS - 1 ? KROWS - 1 : a);   // clamp; masked at store
            sA[c] = a << 4; xA[c] = (a >> 3) & 7;
            int b = (cB << 2) + c - kbase;
            b = b < 0 ? 0 : (b > KROWS - 1 ? KROWS - 1 : b);
            sB[c] = b << 4; xB[c] = (b >> 3) & 7;
        }

        float acc[4][8];
#pragma unroll
        for (int r = 0; r < 4; ++r)
#pragma unroll
            for (int c = 0; c < 8; ++c) acc[r][c] = 0.f;

#pragma unroll 4
        for (int d4 = 0; d4 < D4; ++d4) {
            f4 qv[4], ka[4], kb[4];
#pragma unroll
            for (int r = 0; r < 4; ++r)  qv[r] = Q4[(size_t)(r0 + r) * D4 + d4];
#pragma unroll
            for (int c = 0; c < 4; ++c)  ka[c] = sK[sA[c] + (d4 ^ xA[c])];
#pragma unroll
            for (int c = 0; c < 4; ++c)  kb[c] = sK[sB[c] + (d4 ^ xB[c])];
#pragma unroll
            for (int r = 0; r < 4; ++r) {
                const float qx = qv[r].x, qy = qv[r].y, qz = qv[r].z, qw = qv[r].w;
#pragma unroll
                for (int c = 0; c < 4; ++c) {
                    acc[r][c]     += qx * ka[c].x + qy * ka[c].y + qz * ka[c].z + qw * ka[c].w;
                    acc[r][4 + c] += qx * kb[c].x + qy * kb[c].y + qz * kb[c].z + qw * kb[c].w;
                }
            }
        }

        const int colA = cA << 2, colB = cB << 2;
#pragma unroll
        for (int r = 0; r < 4; ++r) {
            const int i = r0 + r;
            f4 vA, vB;
            vA.x = ((unsigned)(i - (colA + 0) + RAD) <= 2u * RAD) ? acc[r][0] : 0.f;
            vA.y = ((unsigned)(i - (colA + 1) + RAD) <= 2u * RAD) ? acc[r][1] : 0.f;
            vA.z = ((unsigned)(i - (colA + 2) + RAD) <= 2u * RAD) ? acc[r][2] : 0.f;
            vA.w = ((unsigned)(i - (colA + 3) + RAD) <= 2u * RAD) ? acc[r][3] : 0.f;
            vB.x = ((unsigned)(i - (colB + 0) + RAD) <= 2u * RAD) ? acc[r][4] : 0.f;
            vB.y = ((unsigned)(i - (colB + 1) + RAD) <= 2u * RAD) ? acc[r][5] : 0.f;
            vB.z = ((unsigned)(i - (colB + 2) + RAD) <= 2u * RAD) ? acc[r][6] : 0.f;
            vB.w = ((unsigned)(i - (colB + 3) + RAD) <= 2u * RAD) ? acc[r][7] : 0.f;
            __builtin_nontemporal_store(vA, O4 + (size_t)i * NC4 + cA);
            __builtin_nontemporal_store(vB, O4 + (size_t)i * NC4 + cB);
        }
    };

    run_item(t / 34, t % 34);          // items 0..255 (rg = t/34 <= 7)
    if (t < 16) run_item(7, 18 + t);   // items 256..271
}

extern "C" void kernel_launch(void* const* d_in, const int* in_sizes, int n_in,
                              void* d_out, int out_size, void* d_ws, size_t ws_size,
                              hipStream_t stream) {
    const float* Q = (const float*)d_in[0];
    const float* K = (const float*)d_in[1];
    float* out = (float*)d_out;
    zero_oob<<<ZBLK, 256, 0, stream>>>(out);
    band_compute<<<BBLK, 256, 0, stream>>>(Q, K, out);
}

// Round 6
// 224.721 us; speedup vs baseline: 1.4312x; 1.0684x over previous
//
#include <hip/hip_runtime.h>

typedef float f4 __attribute__((ext_vector_type(4)));

#define L_SEQ 2048
#define D4    16             // 64 floats = 16 float4 per K/Q row
#define NC4   512            // float4 chunks per output row
#define RAD   128
#define TI    16             // rows per tile (both roles)
#define NBH   48
#define NTIL  128            // L_SEQ/TI
#define NPER  (NBH * NTIL)   // 6144 blocks per role
#define NBLK  (2 * NPER)     // 12288

// One kernel, two block roles, co-resident on every CU:
//   Z-role: streams zeros for all chunks OUTSIDE [g-32, g+32] per row
//           (g = row>>2) -- pure store loop, keeps the HBM write pipe fed.
//   B-role: computes band values for chunks INSIDE [g-32, g+32] (band-masked),
//           K band + Q tile staged in LDS (R3-proven structure).
// Coverage is disjoint and exact. Role = (bid>>3)&1 so that the XCD
// round-robin (bid%8) sees alternating role-groups, never segregation.
// LDS = 40960 B exactly -> 4 blocks/CU.
__global__ __launch_bounds__(256, 4)
void band_fused(const float* __restrict__ Qg, const float* __restrict__ Kg,
                float* __restrict__ outg)
{
    __shared__ f4 sK[144 * D4];   // 36864 B, slot = si*16 + (d4 ^ ((si>>2)&7))
    __shared__ f4 sQ[TI * D4];    //  4096 B, slot = row*16 + (d4 ^ row)

    const int t   = threadIdx.x;
    const int bid = blockIdx.x;
    const int role = (bid >> 3) & 1;
    const int sub  = ((bid >> 4) << 3) | (bid & 7);   // [0, NPER)

    if (role == 0) {
        // ================= Z: zero-stream out-of-band =================
        const int bh = sub >> 7;
        const int r0 = (sub & 127) * TI;
        f4* __restrict__ O4 = reinterpret_cast<f4*>(outg) + (size_t)bh * L_SEQ * NC4;
        const f4 zero = (f4)0.f;
#pragma unroll
        for (int r = 0; r < TI; ++r) {
            const int i = r0 + r;
            const int g = i >> 2;
            int L = g - 32; L = L < 0 ? 0 : L;
            int H = g + 32; H = H > NC4 - 1 ? NC4 - 1 : H;
            const int skip = H - L + 1;          // 33..65
            const int zc   = NC4 - skip;         // 447..479 zero chunks
            f4* rowp = O4 + (size_t)i * NC4;
            const int jA = t < L ? t : t + skip;
            rowp[jA] = zero;                     // t < zc always (zc >= 447)
            const int k2 = t + 256;
            if (k2 < zc) {
                const int jB = k2 < L ? k2 : k2 + skip;
                rowp[jB] = zero;
            }
        }
        return;
    }

    // ================= B: band compute (R3 structure) =================
    // bijective XCD swizzle (NPER % 8 == 0): same-bh blocks share an XCD's L2
    const int swz = (sub & 7) * (NPER / 8) + (sub >> 3);
    const int bh  = swz >> 7;
    const int i0  = (swz & (NTIL - 1)) * TI;
    const int i04 = i0 >> 2;

    const f4* __restrict__ K4 = reinterpret_cast<const f4*>(Kg) + (size_t)bh * L_SEQ * D4;
    const f4* __restrict__ Q4 = reinterpret_cast<const f4*>(Qg) + (size_t)bh * L_SEQ * D4;
    f4* __restrict__ O4       = reinterpret_cast<f4*>(outg)     + (size_t)bh * L_SEQ * NC4;

    // ---- stage Q tile (16 rows x 64), swizzled
    {
        const int row = t >> 4, d4 = t & 15;
        const f4 v = Q4[(i0 + row) * D4 + d4];
        sQ[(row << 4) + (d4 ^ row)] = v;
    }

    // ---- stage K phase 0: global rows [i0-128, i0+16) (si = 0..143)
    const int kb0 = i0 - RAD;
#pragma unroll
    for (int itr = 0; itr < 9; ++itr) {
        const int s  = itr * 256 + t;
        const int si = s >> 4, d4 = s & 15;
        int row = kb0 + si;
        row = row < 0 ? 0 : row;            // clamp; clamped slots never read (guarded)
        const f4 v = K4[(size_t)row * D4 + d4];
        sK[(si << 4) + (d4 ^ ((si >> 2) & 7))] = v;
    }
    __syncthreads();

    // ---- phase 0: items (rg, cb), j4 = i04+rg-32+cb, cb <= 35-rg
    {
        const int rg = t / 36;
        const int cb = t - rg * 36;
        const int j4 = i04 + rg - 32 + cb;
        if (t < 144 && cb <= 35 - rg && j4 >= 0) {
            const int rg4 = rg << 2;
            const int sb  = (rg + cb) << 2;
            const int x   = (rg + cb) & 7;
            float acc[4][4];
#pragma unroll
            for (int r = 0; r < 4; ++r)
#pragma unroll
                for (int c = 0; c < 4; ++c) acc[r][c] = 0.f;
#pragma unroll 4
            for (int d4 = 0; d4 < D4; ++d4) {
                const int dk = d4 ^ x;
                f4 kv[4], qv[4];
#pragma unroll
                for (int c = 0; c < 4; ++c) kv[c] = sK[((sb + c) << 4) + dk];
#pragma unroll
                for (int r = 0; r < 4; ++r) qv[r] = sQ[((rg4 + r) << 4) + (d4 ^ (rg4 + r))];
#pragma unroll
                for (int r = 0; r < 4; ++r)
#pragma unroll
                    for (int c = 0; c < 4; ++c)
                        acc[r][c] += qv[r].x * kv[c].x + qv[r].y * kv[c].y
                                   + qv[r].z * kv[c].z + qv[r].w * kv[c].w;
            }
            const int c0 = j4 << 2;
#pragma unroll
            for (int r = 0; r < 4; ++r) {
                const int i = i0 + rg4 + r;
                f4 v;
                v.x = ((unsigned)(i - (c0 + 0) + RAD) <= 2u * RAD) ? acc[r][0] : 0.f;
                v.y = ((unsigned)(i - (c0 + 1) + RAD) <= 2u * RAD) ? acc[r][1] : 0.f;
                v.z = ((unsigned)(i - (c0 + 2) + RAD) <= 2u * RAD) ? acc[r][2] : 0.f;
                v.w = ((unsigned)(i - (c0 + 3) + RAD) <= 2u * RAD) ? acc[r][3] : 0.f;
                O4[(size_t)i * NC4 + j4] = v;
            }
        }
    }
    __syncthreads();   // phase-0 LDS reads done before overwrite

    // ---- stage K phase 1: global rows [i0+16, i0+144) (si = 0..127)
    const int kb1 = i0 + TI;
#pragma unroll
    for (int itr = 0; itr < 8; ++itr) {
        const int s  = itr * 256 + t;
        const int si = s >> 4, d4 = s & 15;
        int row = kb1 + si;
        row = row > L_SEQ - 1 ? L_SEQ - 1 : row;   // clamp; never read (guarded)
        const f4 v = K4[(size_t)row * D4 + d4];
        sK[(si << 4) + (d4 ^ ((si >> 2) & 7))] = v;
    }
    __syncthreads();

    // ---- phase 1: items (rg, cb), j4 = i04+4+cb, cb <= 28+rg
    {
        const int rg = t >> 5;
        const int cb = t & 31;
        const int j4 = i04 + 4 + cb;
        if (t < 128 && cb <= 28 + rg && j4 <= NC4 - 1) {
            const int rg4 = rg << 2;
            const int sb  = cb << 2;
            const int x   = cb & 7;
            float acc[4][4];
#pragma unroll
            for (int r = 0; r < 4; ++r)
#pragma unroll
                for (int c = 0; c < 4; ++c) acc[r][c] = 0.f;
#pragma unroll 4
            for (int d4 = 0; d4 < D4; ++d4) {
                const int dk = d4 ^ x;
                f4 kv[4], qv[4];
#pragma unroll
                for (int c = 0; c < 4; ++c) kv[c] = sK[((sb + c) << 4) + dk];
#pragma unroll
                for (int r = 0; r < 4; ++r) qv[r] = sQ[((rg4 + r) << 4) + (d4 ^ (rg4 + r))];
#pragma unroll
                for (int r = 0; r < 4; ++r)
#pragma unroll
                    for (int c = 0; c < 4; ++c)
                        acc[r][c] += qv[r].x * kv[c].x + qv[r].y * kv[c].y
                                   + qv[r].z * kv[c].z + qv[r].w * kv[c].w;
            }
            const int c0 = j4 << 2;
#pragma unroll
            for (int r = 0; r < 4; ++r) {
                const int i = i0 + rg4 + r;
                f4 v;
                v.x = ((unsigned)(i - (c0 + 0) + RAD) <= 2u * RAD) ? acc[r][0] : 0.f;
                v.y = ((unsigned)(i - (c0 + 1) + RAD) <= 2u * RAD) ? acc[r][1] : 0.f;
                v.z = ((unsigned)(i - (c0 + 2) + RAD) <= 2u * RAD) ? acc[r][2] : 0.f;
                v.w = ((unsigned)(i - (c0 + 3) + RAD) <= 2u * RAD) ? acc[r][3] : 0.f;
                O4[(size_t)i * NC4 + j4] = v;
            }
        }
    }
}

extern "C" void kernel_launch(void* const* d_in, const int* in_sizes, int n_in,
                              void* d_out, int out_size, void* d_ws, size_t ws_size,
                              hipStream_t stream) {
    const float* Q = (const float*)d_in[0];
    const float* K = (const float*)d_in[1];
    float* out = (float*)d_out;
    band_fused<<<NBLK, 256, 0, stream>>>(Q, K, out);
}